// Round 2
// baseline (2663.471 us; speedup 1.0000x reference)
//
#include <hip/hip_runtime.h>
#include <hip/hip_bf16.h>

#define HW 192
#define HWHW 36864
#define NB 4

// storage-type load/store helpers (activations may be fp32 or bf16 in ws)
__device__ __forceinline__ float ldT(const float* p, int i) { return p[i]; }
__device__ __forceinline__ float ldT(const __hip_bfloat16* p, int i) { return __bfloat162float(p[i]); }
__device__ __forceinline__ void stT(float* p, int i, float v) { p[i] = v; }
__device__ __forceinline__ void stT(__hip_bfloat16* p, int i, float v) { p[i] = __float2bfloat16(v); }

// ---------------- upflow: transposed conv 2x, groups=2, k=4, pad=2 ----------------
// flow_out (4,2,192,192) fp32  <-  flow_in (4,2,96,96) fp32, w (2,1,4,4) fp32
__global__ void upflow_kernel(const float* __restrict__ fin,
                              const float* __restrict__ w,
                              float* __restrict__ fout) {
    int idx = blockIdx.x * blockDim.x + threadIdx.x;
    if (idx >= NB * 2 * HWHW) return;
    int x = idx % HW;
    int y = (idx / HW) % HW;
    int g = (idx / HWHW) % 2;
    int b = idx / (2 * HWHW);
    float acc = 0.f;
#pragma unroll
    for (int ky = 0; ky < 4; ++ky) {
        int py = y + ky - 2;
        if (py < 0 || py > 190 || (py & 1)) continue;
        int iy = py >> 1;
#pragma unroll
        for (int kx = 0; kx < 4; ++kx) {
            int px = x + kx - 2;
            if (px < 0 || px > 190 || (px & 1)) continue;
            int ix = px >> 1;
            acc += fin[((b * 2 + g) * 96 + iy) * 96 + ix] *
                   w[g * 16 + (3 - ky) * 4 + (3 - kx)];
        }
    }
    fout[idx] = acc;
}

// ---------------- backwarp: bilinear warp of features2 by flow*2.5 ----------------
template <typename T>
__global__ void backwarp_kernel(const float* __restrict__ feat,
                                const float* __restrict__ flow,
                                T* __restrict__ out) {
    int idx = blockIdx.x * blockDim.x + threadIdx.x;
    if (idx >= NB * 96 * HWHW) return;
    int x = idx % HW;
    int y = (idx / HW) % HW;
    int c = (idx / HWHW) % 96;
    int b = idx / (96 * HWHW);
    float fx = flow[((b * 2 + 0) * HW + y) * HW + x] * 2.5f;
    float fy = flow[((b * 2 + 1) * HW + y) * HW + x] * 2.5f;
    float gx = (float)x + fx, gy = (float)y + fy;
    float x0f = floorf(gx), y0f = floorf(gy);
    float wx = gx - x0f, wy = gy - y0f;
    int x0 = (int)x0f, y0 = (int)y0f;
    const float* fb = feat + (size_t)(b * 96 + c) * HWHW;
    bool xv0 = (unsigned)x0 < (unsigned)HW;
    bool xv1 = (unsigned)(x0 + 1) < (unsigned)HW;
    bool yv0 = (unsigned)y0 < (unsigned)HW;
    bool yv1 = (unsigned)(y0 + 1) < (unsigned)HW;
    float v00 = (yv0 && xv0) ? fb[y0 * HW + x0] : 0.f;
    float v01 = (yv0 && xv1) ? fb[y0 * HW + x0 + 1] : 0.f;
    float v10 = (yv1 && xv0) ? fb[(y0 + 1) * HW + x0] : 0.f;
    float v11 = (yv1 && xv1) ? fb[(y0 + 1) * HW + x0 + 1] : 0.f;
    float r = v00 * (1.f - wy) * (1.f - wx) + v01 * (1.f - wy) * wx +
              v10 * wy * (1.f - wx) + v11 * wy * wx;
    stT(out, idx, r);
}

// ---------------- correlation (MD=3 -> 49 disp) + leaky, /96 ----------------
template <typename T>
__global__ __launch_bounds__(256) void corr_kernel(const float* __restrict__ f1,
                                                   const T* __restrict__ f2,
                                                   T* __restrict__ out) {
    __shared__ float s1[16][16][4];
    __shared__ float s2[22][23][4];
    int t = threadIdx.x;
    int tx = t % 16, ty = t / 16;
    int x0 = blockIdx.x * 16, y0 = blockIdx.y * 16, b = blockIdx.z;
    float acc[49];
#pragma unroll
    for (int i = 0; i < 49; ++i) acc[i] = 0.f;

    for (int c0 = 0; c0 < 96; c0 += 4) {
        __syncthreads();
        {
            int gy = y0 + ty, gx = x0 + tx;
#pragma unroll
            for (int i = 0; i < 4; ++i)
                s1[ty][tx][i] = f1[((b * 96 + c0 + i) * HWHW) + gy * HW + gx];
        }
        for (int p = t; p < 22 * 22; p += 256) {
            int ry = p / 22, rx = p % 22;
            int gy = y0 + ry - 3, gx = x0 + rx - 3;
            bool v = ((unsigned)gy < (unsigned)HW) && ((unsigned)gx < (unsigned)HW);
#pragma unroll
            for (int i = 0; i < 4; ++i)
                s2[ry][rx][i] = v ? ldT(f2, ((b * 96 + c0 + i) * HWHW) + gy * HW + gx) : 0.f;
        }
        __syncthreads();
        float4 v1 = *(const float4*)&s1[ty][tx][0];
#pragma unroll
        for (int dy = 0; dy < 7; ++dy) {
#pragma unroll
            for (int dx = 0; dx < 7; ++dx) {
                float4 v2 = *(const float4*)&s2[ty + dy][tx + dx][0];
                acc[dy * 7 + dx] += v1.x * v2.x + v1.y * v2.y + v1.z * v2.z + v1.w * v2.w;
            }
        }
    }
    int gy = y0 + ty, gx = x0 + tx;
#pragma unroll
    for (int d = 0; d < 49; ++d) {
        float v = acc[d] * (1.0f / 96.0f);
        v = v >= 0.f ? v : 0.1f * v;
        stT(out, ((b * 49 + d) * HWHW) + gy * HW + gx, v);
    }
}

// ---------------- generic 3x3 conv, pad 1, + bias + leaky ----------------
// 256 thr = 4 waves; each wave = 8 out-channels; tile 16x16; thread: 4 rows x 8 co
template <typename T>
__global__ __launch_bounds__(256) void conv3_kernel(const T* __restrict__ in,
                                                    const float* __restrict__ wg,
                                                    const float* __restrict__ bias,
                                                    T* __restrict__ out,
                                                    int Cin, int Cout, int leaky) {
    __shared__ float s_in[18][19][4];
    __shared__ float s_w[9][32][4];
    int t = threadIdx.x;
    int lane = t % 64;
    int cog = t / 64;
    int wx = lane % 16;
    int hg = lane / 16;
    int x0 = blockIdx.x * 16, y0 = blockIdx.y * 16;
    int nCoB = Cout / 32;
    int cob = blockIdx.z % nCoB;
    int b = blockIdx.z / nCoB;

    float acc[8][4];
#pragma unroll
    for (int i = 0; i < 8; ++i)
#pragma unroll
        for (int j = 0; j < 4; ++j) acc[i][j] = 0.f;

    for (int c0 = 0; c0 < Cin; c0 += 4) {
        __syncthreads();
        for (int p = t; p < 18 * 18; p += 256) {
            int ry = p / 18, rx = p % 18;
            int gy = y0 + ry - 1, gx = x0 + rx - 1;
            bool v = ((unsigned)gy < (unsigned)HW) && ((unsigned)gx < (unsigned)HW);
#pragma unroll
            for (int i = 0; i < 4; ++i) {
                bool cv = (c0 + i) < Cin;
                s_in[ry][rx][i] = (v && cv)
                    ? ldT(in, ((b * Cin + c0 + i) * HWHW) + gy * HW + gx) : 0.f;
            }
        }
        for (int p = t; p < 9 * 32 * 4; p += 256) {
            int ci = p % 4;
            int co = (p / 4) % 32;
            int k = p / 128;
            bool cv = (c0 + ci) < Cin;
            s_w[k][co][ci] = cv
                ? wg[((cob * 32 + co) * Cin + c0 + ci) * 9 + k] : 0.f;
        }
        __syncthreads();
#pragma unroll
        for (int ky = 0; ky < 3; ++ky) {
#pragma unroll
            for (int kx = 0; kx < 3; ++kx) {
                int k = ky * 3 + kx;
                float4 v[4];
#pragma unroll
                for (int j = 0; j < 4; ++j)
                    v[j] = *(const float4*)&s_in[hg * 4 + j + ky][wx + kx][0];
#pragma unroll
                for (int c8 = 0; c8 < 8; ++c8) {
                    float4 wv = *(const float4*)&s_w[k][cog * 8 + c8][0];
#pragma unroll
                    for (int j = 0; j < 4; ++j)
                        acc[c8][j] += wv.x * v[j].x + wv.y * v[j].y +
                                      wv.z * v[j].z + wv.w * v[j].w;
                }
            }
        }
    }
#pragma unroll
    for (int c8 = 0; c8 < 8; ++c8) {
        int co = cob * 32 + cog * 8 + c8;
        float bv = bias[co];
#pragma unroll
        for (int j = 0; j < 4; ++j) {
            float vv = acc[c8][j] + bv;
            if (leaky) vv = vv >= 0.f ? vv : 0.1f * vv;
            stT(out, ((b * Cout + co) * HWHW) + (y0 + hg * 4 + j) * HW + (x0 + wx), vv);
        }
    }
}

// ---------------- conv4: 5x5, 32->2, pad 2, + bias + flow residual ----------------
template <typename T>
__global__ __launch_bounds__(256) void conv4_kernel(const T* __restrict__ in,
                                                    const float* __restrict__ wg,
                                                    const float* __restrict__ bias,
                                                    const float* __restrict__ flow,
                                                    float* __restrict__ out) {
    __shared__ float s_in[20][21][4];
    __shared__ float s_w[2][25][4];
    int t = threadIdx.x;
    int tx = t % 16, ty = t / 16;
    int x0 = blockIdx.x * 16, y0 = blockIdx.y * 16, b = blockIdx.z;
    float acc0 = 0.f, acc1 = 0.f;
    for (int c0 = 0; c0 < 32; c0 += 4) {
        __syncthreads();
        for (int p = t; p < 20 * 20; p += 256) {
            int ry = p / 20, rx = p % 20;
            int gy = y0 + ry - 2, gx = x0 + rx - 2;
            bool v = ((unsigned)gy < (unsigned)HW) && ((unsigned)gx < (unsigned)HW);
#pragma unroll
            for (int i = 0; i < 4; ++i)
                s_in[ry][rx][i] = v ? ldT(in, ((b * 32 + c0 + i) * HWHW) + gy * HW + gx) : 0.f;
        }
        if (t < 200) {
            int ci = t % 4, k = (t / 4) % 25, co = t / 100;
            s_w[co][k][ci] = wg[(co * 32 + c0 + ci) * 25 + k];
        }
        __syncthreads();
#pragma unroll
        for (int ky = 0; ky < 5; ++ky) {
#pragma unroll
            for (int kx = 0; kx < 5; ++kx) {
                float4 v = *(const float4*)&s_in[ty + ky][tx + kx][0];
                float4 w0 = *(const float4*)&s_w[0][ky * 5 + kx][0];
                float4 w1 = *(const float4*)&s_w[1][ky * 5 + kx][0];
                acc0 += v.x * w0.x + v.y * w0.y + v.z * w0.z + v.w * w0.w;
                acc1 += v.x * w1.x + v.y * w1.y + v.z * w1.z + v.w * w1.w;
            }
        }
    }
    int gy = y0 + ty, gx = x0 + tx;
    int o0 = ((b * 2 + 0) * HWHW) + gy * HW + gx;
    int o1 = ((b * 2 + 1) * HWHW) + gy * HW + gx;
    out[o0] = acc0 + bias[0] + flow[o0];
    out[o1] = acc1 + bias[1] + flow[o1];
}

// region sizes (elements)
#define A_ELEMS 18874368ull   // max(feat2 14.2M, x1 18.9M, x3 4.7M)
#define B_ELEMS 9437184ull    // max(corr 7.2M, x2 9.4M)
#define FLOW_BYTES 1179648ull

template <typename T>
static void run_all(const float* f1, const float* f2in, const float* flow_in,
                    const float* w_up, const float* w1, const float* b1,
                    const float* w2, const float* b2, const float* w3,
                    const float* b3, const float* w4, const float* b4,
                    float* out, char* ws, hipStream_t stream) {
    float* flow = (float*)ws;
    T* A = (T*)(ws + FLOW_BYTES);
    T* B = (T*)(ws + FLOW_BYTES + A_ELEMS * sizeof(T));
    // ping-pong: feat2->A, corr->B, x1->A, x2->B, x3->A
    upflow_kernel<<<(NB * 2 * HWHW + 255) / 256, 256, 0, stream>>>(flow_in, w_up, flow);
    backwarp_kernel<T><<<(NB * 96 * HWHW + 255) / 256, 256, 0, stream>>>(f2in, flow, A);
    corr_kernel<T><<<dim3(12, 12, NB), 256, 0, stream>>>(f1, A, B);
    conv3_kernel<T><<<dim3(12, 12, NB * 4), 256, 0, stream>>>(B, w1, b1, A, 49, 128, 1);
    conv3_kernel<T><<<dim3(12, 12, NB * 2), 256, 0, stream>>>(A, w2, b2, B, 128, 64, 1);
    conv3_kernel<T><<<dim3(12, 12, NB * 1), 256, 0, stream>>>(B, w3, b3, A, 64, 32, 1);
    conv4_kernel<T><<<dim3(12, 12, NB), 256, 0, stream>>>(A, w4, b4, flow, out);
}

extern "C" void kernel_launch(void* const* d_in, const int* in_sizes, int n_in,
                              void* d_out, int out_size, void* d_ws, size_t ws_size,
                              hipStream_t stream) {
    (void)in_sizes; (void)n_in; (void)out_size;
    const float* f1      = (const float*)d_in[2];
    const float* f2in    = (const float*)d_in[3];
    const float* flow_in = (const float*)d_in[4];
    const float* w_up    = (const float*)d_in[5];
    const float* w1      = (const float*)d_in[6];
    const float* b1      = (const float*)d_in[7];
    const float* w2      = (const float*)d_in[8];
    const float* b2      = (const float*)d_in[9];
    const float* w3      = (const float*)d_in[10];
    const float* b3      = (const float*)d_in[11];
    const float* w4      = (const float*)d_in[12];
    const float* b4      = (const float*)d_in[13];
    float* out = (float*)d_out;
    char* ws = (char*)d_ws;

    const size_t need_f32 = FLOW_BYTES + (A_ELEMS + B_ELEMS) * 4;  // 114.4 MB
    if (ws_size >= need_f32) {
        run_all<float>(f1, f2in, flow_in, w_up, w1, b1, w2, b2, w3, b3, w4, b4,
                       out, ws, stream);
    } else {
        run_all<__hip_bfloat16>(f1, f2in, flow_in, w_up, w1, b1, w2, b2, w3, b3,
                                w4, b4, out, ws, stream);
    }
}

// Round 3
// 616.598 us; speedup vs baseline: 4.3196x; 4.3196x over previous
//
#include <hip/hip_runtime.h>
#include <hip/hip_bf16.h>

#define HW 192
#define HWHW 36864
#define NB 4

typedef __attribute__((ext_vector_type(8))) short short8;
typedef __attribute__((ext_vector_type(4))) float floatx4;

__device__ __forceinline__ unsigned pack_bf2(float a, float b) {
    __hip_bfloat162 h = __float22bfloat162_rn(make_float2(a, b));
    return *(unsigned*)&h;
}
__device__ __forceinline__ float4 ld_bf16x4(const __hip_bfloat16* p) {
    uint2 u = *(const uint2*)p;
    __hip_bfloat162 a = *(__hip_bfloat162*)&u.x;
    __hip_bfloat162 b = *(__hip_bfloat162*)&u.y;
    float2 fa = __bfloat1622float2(a), fb = __bfloat1622float2(b);
    return make_float4(fa.x, fa.y, fb.x, fb.y);
}
__device__ __forceinline__ void st_bf16x4(__hip_bfloat16* p, float4 v) {
    uint2 u;
    u.x = pack_bf2(v.x, v.y);
    u.y = pack_bf2(v.z, v.w);
    *(uint2*)p = u;
}

// ---------------- upflow: transposed conv 2x, groups=2, k=4, pad=2 ----------------
__global__ void upflow_kernel(const float* __restrict__ fin,
                              const float* __restrict__ w,
                              float* __restrict__ fout) {
    int idx = blockIdx.x * blockDim.x + threadIdx.x;
    if (idx >= NB * 2 * HWHW) return;
    int x = idx % HW;
    int y = (idx / HW) % HW;
    int g = (idx / HWHW) % 2;
    int b = idx / (2 * HWHW);
    float acc = 0.f;
#pragma unroll
    for (int ky = 0; ky < 4; ++ky) {
        int py = y + ky - 2;
        if (py < 0 || py > 190 || (py & 1)) continue;
        int iy = py >> 1;
#pragma unroll
        for (int kx = 0; kx < 4; ++kx) {
            int px = x + kx - 2;
            if (px < 0 || px > 190 || (px & 1)) continue;
            int ix = px >> 1;
            acc += fin[((b * 2 + g) * 96 + iy) * 96 + ix] *
                   w[g * 16 + (3 - ky) * 4 + (3 - kx)];
        }
    }
    fout[idx] = acc;
}

// ---------------- weight prep: fp32 [CO][CI][3][3] -> bf16 [9][CO][CIP] ----------------
__global__ void wprep_kernel(const float* __restrict__ w, __hip_bfloat16* __restrict__ out,
                             int CO, int CI, int CIP) {
    int idx = blockIdx.x * blockDim.x + threadIdx.x;
    int n = 9 * CO * CIP;
    if (idx >= n) return;
    int ci = idx % CIP;
    int co = (idx / CIP) % CO;
    int k9 = idx / (CIP * CO);
    float v = (ci < CI) ? w[(co * CI + ci) * 9 + k9] : 0.f;
    out[idx] = __float2bfloat16(v);
}

// ---------------- backwarp: thread per pixel, NCHW fp32 -> NHWC96 bf16 ----------------
__global__ __launch_bounds__(256) void backwarp_kernel(const float* __restrict__ feat,
                                                       const float* __restrict__ flow,
                                                       __hip_bfloat16* __restrict__ out) {
    int p = blockIdx.x * blockDim.x + threadIdx.x;
    if (p >= NB * HWHW) return;
    int x = p % HW;
    int y = (p / HW) % HW;
    int b = p / HWHW;
    float fx = flow[((b * 2 + 0) * HW + y) * HW + x] * 2.5f;
    float fy = flow[((b * 2 + 1) * HW + y) * HW + x] * 2.5f;
    float gx = (float)x + fx, gy = (float)y + fy;
    float x0f = floorf(gx), y0f = floorf(gy);
    float wx = gx - x0f, wy = gy - y0f;
    int x0 = (int)x0f, y0 = (int)y0f;
    bool xv0 = (unsigned)x0 < (unsigned)HW;
    bool xv1 = (unsigned)(x0 + 1) < (unsigned)HW;
    bool yv0 = (unsigned)y0 < (unsigned)HW;
    bool yv1 = (unsigned)(y0 + 1) < (unsigned)HW;
    float w00 = (1.f - wy) * (1.f - wx) * ((yv0 && xv0) ? 1.f : 0.f);
    float w01 = (1.f - wy) * wx * ((yv0 && xv1) ? 1.f : 0.f);
    float w10 = wy * (1.f - wx) * ((yv1 && xv0) ? 1.f : 0.f);
    float w11 = wy * wx * ((yv1 && xv1) ? 1.f : 0.f);
    int xc0 = min(max(x0, 0), HW - 1), xc1 = min(max(x0 + 1, 0), HW - 1);
    int yc0 = min(max(y0, 0), HW - 1), yc1 = min(max(y0 + 1, 0), HW - 1);
    const float* fb = feat + (size_t)b * 96 * HWHW;
    int i00 = yc0 * HW + xc0, i01 = yc0 * HW + xc1;
    int i10 = yc1 * HW + xc0, i11 = yc1 * HW + xc1;
    __hip_bfloat16* op = out + (size_t)p * 96;
#pragma unroll 1
    for (int c = 0; c < 96; c += 8) {
        float r[8];
#pragma unroll
        for (int j = 0; j < 8; ++j) {
            const float* fc = fb + (size_t)(c + j) * HWHW;
            r[j] = w00 * fc[i00] + w01 * fc[i01] + w10 * fc[i10] + w11 * fc[i11];
        }
        uint4 u;
        u.x = pack_bf2(r[0], r[1]);
        u.y = pack_bf2(r[2], r[3]);
        u.z = pack_bf2(r[4], r[5]);
        u.w = pack_bf2(r[6], r[7]);
        *(uint4*)&op[c] = u;
    }
}

// ---------------- correlation + leaky, /96 : f1 NCHW fp32, f2 NHWC96 bf16 -> NHWC64 bf16 ----------------
__global__ __launch_bounds__(256) void corr_kernel(const float* __restrict__ f1,
                                                   const __hip_bfloat16* __restrict__ f2,
                                                   __hip_bfloat16* __restrict__ out) {
    __shared__ float s1[16][16][4];
    __shared__ float s2[22][23][4];
    int t = threadIdx.x;
    int tx = t % 16, ty = t / 16;
    int x0 = blockIdx.x * 16, y0 = blockIdx.y * 16, b = blockIdx.z;
    float acc[49];
#pragma unroll
    for (int i = 0; i < 49; ++i) acc[i] = 0.f;

    for (int c0 = 0; c0 < 96; c0 += 4) {
        __syncthreads();
        {
            int gy = y0 + ty, gx = x0 + tx;
#pragma unroll
            for (int i = 0; i < 4; ++i)
                s1[ty][tx][i] = f1[((b * 96 + c0 + i) * HWHW) + gy * HW + gx];
        }
        for (int p = t; p < 22 * 22; p += 256) {
            int ry = p / 22, rx = p % 22;
            int gy = y0 + ry - 3, gx = x0 + rx - 3;
            bool v = ((unsigned)gy < (unsigned)HW) && ((unsigned)gx < (unsigned)HW);
            float4 vv = make_float4(0.f, 0.f, 0.f, 0.f);
            if (v) vv = ld_bf16x4(&f2[(size_t)((b * HW + gy) * HW + gx) * 96 + c0]);
            *(float4*)&s2[ry][rx][0] = vv;
        }
        __syncthreads();
        float4 v1 = *(const float4*)&s1[ty][tx][0];
#pragma unroll
        for (int dy = 0; dy < 7; ++dy) {
#pragma unroll
            for (int dx = 0; dx < 7; ++dx) {
                float4 v2 = *(const float4*)&s2[ty + dy][tx + dx][0];
                acc[dy * 7 + dx] += v1.x * v2.x + v1.y * v2.y + v1.z * v2.z + v1.w * v2.w;
            }
        }
    }
    int gy = y0 + ty, gx = x0 + tx;
    __hip_bfloat16* op = out + (size_t)((b * HW + gy) * HW + gx) * 64;
#pragma unroll
    for (int d0 = 0; d0 < 64; d0 += 4) {
        float4 v;
        float vv[4];
#pragma unroll
        for (int j = 0; j < 4; ++j) {
            int d = d0 + j;
            float a = (d < 49) ? acc[d] * (1.0f / 96.0f) : 0.f;
            a = a >= 0.f ? a : 0.1f * a;
            vv[j] = a;
        }
        v = make_float4(vv[0], vv[1], vv[2], vv[3]);
        st_bf16x4(op + d0, v);
    }
}

// ---------------- MFMA implicit-GEMM 3x3 conv, pad 1, NHWC bf16 -> NHWC bf16 ----------------
// wave tile 32px x 32co (2x2 MFMA 16x16x32 tiles); block = 4 waves
// WCO waves along co, WPX=4/WCO along pixels; block = (WPX*4 rows x 8 cols) x (WCO*32 co)
template <int CIN, int COUT, int WCO, int LEAKY>
__global__ __launch_bounds__(256) void convk(const __hip_bfloat16* __restrict__ in,
                                             const __hip_bfloat16* __restrict__ wg,
                                             const float* __restrict__ bias,
                                             __hip_bfloat16* __restrict__ out) {
    constexpr int WPX = 4 / WCO;
    constexpr int COT = WCO * 32;
    constexpr int BR = WPX * 4;
    constexpr int TH = BR + 2;
    constexpr int NPIX = TH * 10;
    constexpr int CIS = 40;  // 32 ci + 8 pad (80B stride -> conflict-free-ish)
    constexpr int NCOB = COUT / COT;
    __shared__ __hip_bfloat16 s_in[NPIX * CIS];
    __shared__ __hip_bfloat16 s_w[9 * COT * 32];

    const int t = threadIdx.x;
    const int lane = t & 63;
    const int wave = t >> 6;
    const int q = lane >> 4;
    const int l16 = lane & 15;
    const int wpy = wave % WPX;
    const int wco = wave / WPX;
    const int x0 = blockIdx.x * 8;
    const int y0 = blockIdx.y * BR;
    const int cob = (blockIdx.z % NCOB) * COT;
    const int b = blockIdx.z / NCOB;

    floatx4 acc[2][2];
#pragma unroll
    for (int i = 0; i < 2; ++i)
#pragma unroll
        for (int j = 0; j < 2; ++j) acc[i][j] = (floatx4){0.f, 0.f, 0.f, 0.f};

    const int r0 = wpy * 4 + (l16 >> 3);  // pixel row within block (tile i adds 2*i)
    const int pc = l16 & 7;               // pixel col within block

    for (int ci0 = 0; ci0 < CIN; ci0 += 32) {
        __syncthreads();
        // stage input spatial tile x 32 ci  (global NHWC, 16B chunks)
        for (int ch = t; ch < NPIX * 4; ch += 256) {
            int px = ch >> 2;
            int c8 = (ch & 3) * 8;
            int row = px / 10, col = px % 10;
            int gy = y0 + row - 1, gx = x0 + col - 1;
            uint4 u = make_uint4(0u, 0u, 0u, 0u);
            if ((unsigned)gy < (unsigned)HW && (unsigned)gx < (unsigned)HW)
                u = *(const uint4*)&in[(size_t)((b * HW + gy) * HW + gx) * CIN + ci0 + c8];
            *(uint4*)&s_in[px * CIS + c8] = u;
        }
        // stage weights [9][COT][32] for this ci chunk
        for (int ch = t; ch < 9 * COT * 4; ch += 256) {
            int cil = (ch & 3) * 8;
            int co = (ch >> 2) % COT;
            int k9 = ch / (COT * 4);
            *(uint4*)&s_w[(k9 * COT + co) * 32 + cil] =
                *(const uint4*)&wg[(size_t)(k9 * COUT + cob + co) * CIN + ci0 + cil];
        }
        __syncthreads();
#pragma unroll
        for (int k9 = 0; k9 < 9; ++k9) {
            const int ky = k9 / 3, kx = k9 % 3;
            short8 a0 = *(const short8*)&s_w[(k9 * COT + wco * 32 + l16) * 32 + q * 8];
            short8 a1 = *(const short8*)&s_w[(k9 * COT + wco * 32 + 16 + l16) * 32 + q * 8];
            short8 b0 = *(const short8*)&s_in[((r0 + ky) * 10 + pc + kx) * CIS + q * 8];
            short8 b1 = *(const short8*)&s_in[((r0 + 2 + ky) * 10 + pc + kx) * CIS + q * 8];
            acc[0][0] = __builtin_amdgcn_mfma_f32_16x16x32_bf16(a0, b0, acc[0][0], 0, 0, 0);
            acc[0][1] = __builtin_amdgcn_mfma_f32_16x16x32_bf16(a1, b0, acc[0][1], 0, 0, 0);
            acc[1][0] = __builtin_amdgcn_mfma_f32_16x16x32_bf16(a0, b1, acc[1][0], 0, 0, 0);
            acc[1][1] = __builtin_amdgcn_mfma_f32_16x16x32_bf16(a1, b1, acc[1][1], 0, 0, 0);
        }
    }
    // epilogue: D col = lane&15 -> pixel, row = q*4+reg -> co
#pragma unroll
    for (int i = 0; i < 2; ++i) {
        int y = y0 + r0 + i * 2;
        int x = x0 + pc;
        size_t pixbase = (size_t)((b * HW + y) * HW + x) * COUT;
#pragma unroll
        for (int j = 0; j < 2; ++j) {
            int co4 = cob + wco * 32 + j * 16 + q * 4;
            float4 bv = *(const float4*)&bias[co4];
            float r[4];
#pragma unroll
            for (int reg = 0; reg < 4; ++reg) {
                float vv = acc[i][j][reg] + ((const float*)&bv)[reg];
                if (LEAKY) vv = vv >= 0.f ? vv : 0.1f * vv;
                r[reg] = vv;
            }
            uint2 u;
            u.x = pack_bf2(r[0], r[1]);
            u.y = pack_bf2(r[2], r[3]);
            *(uint2*)&out[pixbase + co4] = u;
        }
    }
}

// ---------------- conv4: 5x5, 32->2, pad 2, NHWC32 bf16 in, + bias + flow residual ----------------
__global__ __launch_bounds__(256) void conv4_kernel(const __hip_bfloat16* __restrict__ in,
                                                    const float* __restrict__ wg,
                                                    const float* __restrict__ bias,
                                                    const float* __restrict__ flow,
                                                    float* __restrict__ out) {
    __shared__ float s_in[20 * 20 * 36];
    __shared__ float s_w[2 * 25 * 32];
    int t = threadIdx.x;
    int tx = t % 16, ty = t / 16;
    int x0 = blockIdx.x * 16, y0 = blockIdx.y * 16, b = blockIdx.z;
    // stage input tile 20x20 x 32ci
    for (int ch = t; ch < 400 * 4; ch += 256) {
        int px = ch >> 2;
        int c8 = (ch & 3) * 8;
        int ry = px / 20, rx = px % 20;
        int gy = y0 + ry - 2, gx = x0 + rx - 2;
        float4 lo = make_float4(0.f, 0.f, 0.f, 0.f), hi = lo;
        if ((unsigned)gy < (unsigned)HW && (unsigned)gx < (unsigned)HW) {
            const __hip_bfloat16* p = &in[(size_t)((b * HW + gy) * HW + gx) * 32 + c8];
            lo = ld_bf16x4(p);
            hi = ld_bf16x4(p + 4);
        }
        *(float4*)&s_in[px * 36 + c8] = lo;
        *(float4*)&s_in[px * 36 + c8 + 4] = hi;
    }
    // stage weights [2][25][32]
    for (int p = t; p < 1600; p += 256) {
        int ci = p % 32;
        int k = (p / 32) % 25;
        int co = p / 800;
        s_w[(co * 25 + k) * 32 + ci] = wg[(co * 32 + ci) * 25 + k];
    }
    __syncthreads();
    float acc0 = 0.f, acc1 = 0.f;
#pragma unroll
    for (int ky = 0; ky < 5; ++ky) {
#pragma unroll
        for (int kx = 0; kx < 5; ++kx) {
            int k = ky * 5 + kx;
            int base = ((ty + ky) * 20 + tx + kx) * 36;
#pragma unroll
            for (int c4 = 0; c4 < 32; c4 += 4) {
                float4 v = *(const float4*)&s_in[base + c4];
                float4 w0 = *(const float4*)&s_w[(0 * 25 + k) * 32 + c4];
                float4 w1 = *(const float4*)&s_w[(1 * 25 + k) * 32 + c4];
                acc0 += v.x * w0.x + v.y * w0.y + v.z * w0.z + v.w * w0.w;
                acc1 += v.x * w1.x + v.y * w1.y + v.z * w1.z + v.w * w1.w;
            }
        }
    }
    int gy = y0 + ty, gx = x0 + tx;
    int o0 = ((b * 2 + 0) * HWHW) + gy * HW + gx;
    int o1 = ((b * 2 + 1) * HWHW) + gy * HW + gx;
    out[o0] = acc0 + bias[0] + flow[o0];
    out[o1] = acc1 + bias[1] + flow[o1];
}

extern "C" void kernel_launch(void* const* d_in, const int* in_sizes, int n_in,
                              void* d_out, int out_size, void* d_ws, size_t ws_size,
                              hipStream_t stream) {
    (void)in_sizes; (void)n_in; (void)out_size; (void)ws_size;
    const float* f1      = (const float*)d_in[2];
    const float* f2in    = (const float*)d_in[3];
    const float* flow_in = (const float*)d_in[4];
    const float* w_up    = (const float*)d_in[5];
    const float* w1      = (const float*)d_in[6];
    const float* b1      = (const float*)d_in[7];
    const float* w2      = (const float*)d_in[8];
    const float* b2      = (const float*)d_in[9];
    const float* w3      = (const float*)d_in[10];
    const float* b3      = (const float*)d_in[11];
    const float* w4      = (const float*)d_in[12];
    const float* b4      = (const float*)d_in[13];
    float* out = (float*)d_out;
    char* ws = (char*)d_ws;

    // ws layout (bytes):
    //   flow fp32 NCHW        [0, 1179648)
    //   w1b bf16 [9][128][64] [1179648, 1327104)
    //   w2b bf16 [9][64][128] [1327104, 1474560)
    //   w3b bf16 [9][32][64]  [1474560, 1511424)
    //   R1: feat2 NHWC96 / x1 NHWC128  [1511424, +37748736)
    //   R2: corr NHWC64  / x2 NHWC64   [39260160, +18874368)
    //   R3: x3 NHWC32                  [58134528, +9437184)   total 67.5 MB
    float* flow = (float*)ws;
    __hip_bfloat16* w1b = (__hip_bfloat16*)(ws + 1179648);
    __hip_bfloat16* w2b = (__hip_bfloat16*)(ws + 1327104);
    __hip_bfloat16* w3b = (__hip_bfloat16*)(ws + 1474560);
    __hip_bfloat16* R1  = (__hip_bfloat16*)(ws + 1511424);
    __hip_bfloat16* R2  = (__hip_bfloat16*)(ws + 39260160);
    __hip_bfloat16* R3  = (__hip_bfloat16*)(ws + 58134528);

    upflow_kernel<<<1152, 256, 0, stream>>>(flow_in, w_up, flow);
    wprep_kernel<<<288, 256, 0, stream>>>(w1, w1b, 128, 49, 64);
    wprep_kernel<<<288, 256, 0, stream>>>(w2, w2b, 64, 128, 128);
    wprep_kernel<<<72, 256, 0, stream>>>(w3, w3b, 32, 64, 64);
    backwarp_kernel<<<576, 256, 0, stream>>>(f2in, flow, R1);
    corr_kernel<<<dim3(12, 12, NB), 256, 0, stream>>>(f1, R1, R2);
    convk<64, 128, 2, 1><<<dim3(24, 24, NB * 2), 256, 0, stream>>>(R2, w1b, b1, R1);
    convk<128, 64, 2, 1><<<dim3(24, 24, NB), 256, 0, stream>>>(R1, w2b, b2, R2);
    convk<64, 32, 1, 1><<<dim3(24, 12, NB), 256, 0, stream>>>(R2, w3b, b3, R3);
    conv4_kernel<<<dim3(12, 12, NB), 256, 0, stream>>>(R3, w4, b4, flow, out);
}

// Round 4
// 588.947 us; speedup vs baseline: 4.5224x; 1.0469x over previous
//
#include <hip/hip_runtime.h>
#include <hip/hip_bf16.h>

#define HW 192
#define HWHW 36864
#define NB 4

typedef __attribute__((ext_vector_type(8))) short short8;
typedef __attribute__((ext_vector_type(4))) float floatx4;

__device__ __forceinline__ unsigned pack_bf2(float a, float b) {
    __hip_bfloat162 h = __float22bfloat162_rn(make_float2(a, b));
    return *(unsigned*)&h;
}
__device__ __forceinline__ float4 ld_bf16x4(const __hip_bfloat16* p) {
    uint2 u = *(const uint2*)p;
    __hip_bfloat162 a = *(__hip_bfloat162*)&u.x;
    __hip_bfloat162 b = *(__hip_bfloat162*)&u.y;
    float2 fa = __bfloat1622float2(a), fb = __bfloat1622float2(b);
    return make_float4(fa.x, fa.y, fb.x, fb.y);
}
__device__ __forceinline__ void st_bf16x4(__hip_bfloat16* p, float4 v) {
    uint2 u;
    u.x = pack_bf2(v.x, v.y);
    u.y = pack_bf2(v.z, v.w);
    *(uint2*)p = u;
}

// ---------------- upflow ----------------
__global__ void upflow_kernel(const float* __restrict__ fin,
                              const float* __restrict__ w,
                              float* __restrict__ fout) {
    int idx = blockIdx.x * blockDim.x + threadIdx.x;
    if (idx >= NB * 2 * HWHW) return;
    int x = idx % HW;
    int y = (idx / HW) % HW;
    int g = (idx / HWHW) % 2;
    int b = idx / (2 * HWHW);
    float acc = 0.f;
#pragma unroll
    for (int ky = 0; ky < 4; ++ky) {
        int py = y + ky - 2;
        if (py < 0 || py > 190 || (py & 1)) continue;
        int iy = py >> 1;
#pragma unroll
        for (int kx = 0; kx < 4; ++kx) {
            int px = x + kx - 2;
            if (px < 0 || px > 190 || (px & 1)) continue;
            int ix = px >> 1;
            acc += fin[((b * 2 + g) * 96 + iy) * 96 + ix] *
                   w[g * 16 + (3 - ky) * 4 + (3 - kx)];
        }
    }
    fout[idx] = acc;
}

// ---------------- weight prep: fp32 [CO][CI][3][3] -> bf16 [9][CO][CIP] ----------------
__global__ void wprep_kernel(const float* __restrict__ w, __hip_bfloat16* __restrict__ out,
                             int CO, int CI, int CIP) {
    int idx = blockIdx.x * blockDim.x + threadIdx.x;
    int n = 9 * CO * CIP;
    if (idx >= n) return;
    int ci = idx % CIP;
    int co = (idx / CIP) % CO;
    int k9 = idx / (CIP * CO);
    float v = (ci < CI) ? w[(co * CI + ci) * 9 + k9] : 0.f;
    out[idx] = __float2bfloat16(v);
}

// ---------------- backwarp: px-thread x 4 channel-groups, NCHW fp32 -> NHWC96 bf16 ----------------
__global__ __launch_bounds__(256) void backwarp_kernel(const float* __restrict__ feat,
                                                       const float* __restrict__ flow,
                                                       __hip_bfloat16* __restrict__ out) {
    int p = blockIdx.x * blockDim.x + threadIdx.x;
    if (p >= NB * HWHW) return;
    int cg = blockIdx.y;  // channel group: 24 channels
    int x = p % HW;
    int y = (p / HW) % HW;
    int b = p / HWHW;
    float fx = flow[((b * 2 + 0) * HW + y) * HW + x] * 2.5f;
    float fy = flow[((b * 2 + 1) * HW + y) * HW + x] * 2.5f;
    float gx = (float)x + fx, gy = (float)y + fy;
    float x0f = floorf(gx), y0f = floorf(gy);
    float wx = gx - x0f, wy = gy - y0f;
    int x0 = (int)x0f, y0 = (int)y0f;
    bool xv0 = (unsigned)x0 < (unsigned)HW;
    bool xv1 = (unsigned)(x0 + 1) < (unsigned)HW;
    bool yv0 = (unsigned)y0 < (unsigned)HW;
    bool yv1 = (unsigned)(y0 + 1) < (unsigned)HW;
    float w00 = (1.f - wy) * (1.f - wx) * ((yv0 && xv0) ? 1.f : 0.f);
    float w01 = (1.f - wy) * wx * ((yv0 && xv1) ? 1.f : 0.f);
    float w10 = wy * (1.f - wx) * ((yv1 && xv0) ? 1.f : 0.f);
    float w11 = wy * wx * ((yv1 && xv1) ? 1.f : 0.f);
    int xc0 = min(max(x0, 0), HW - 1), xc1 = min(max(x0 + 1, 0), HW - 1);
    int yc0 = min(max(y0, 0), HW - 1), yc1 = min(max(y0 + 1, 0), HW - 1);
    const float* fb = feat + (size_t)b * 96 * HWHW + (size_t)cg * 24 * HWHW;
    int i00 = yc0 * HW + xc0, i01 = yc0 * HW + xc1;
    int i10 = yc1 * HW + xc0, i11 = yc1 * HW + xc1;
    __hip_bfloat16* op = out + (size_t)p * 96 + cg * 24;
#pragma unroll
    for (int c = 0; c < 24; c += 8) {
        float r[8];
#pragma unroll
        for (int j = 0; j < 8; ++j) {
            const float* fc = fb + (size_t)(c + j) * HWHW;
            r[j] = w00 * fc[i00] + w01 * fc[i01] + w10 * fc[i10] + w11 * fc[i11];
        }
        uint4 u;
        u.x = pack_bf2(r[0], r[1]);
        u.y = pack_bf2(r[2], r[3]);
        u.z = pack_bf2(r[4], r[5]);
        u.w = pack_bf2(r[6], r[7]);
        *(uint4*)&op[c] = u;
    }
}

// ---------------- correlation + leaky, /96 : f1 NCHW fp32, f2 NHWC96 bf16 -> NHWC64 bf16 ----------------
__global__ __launch_bounds__(256) void corr_kernel(const float* __restrict__ f1,
                                                   const __hip_bfloat16* __restrict__ f2,
                                                   __hip_bfloat16* __restrict__ out) {
    __shared__ float s1[16][16][4];
    __shared__ float s2[22][23][4];
    int t = threadIdx.x;
    int tx = t % 16, ty = t / 16;
    int x0 = blockIdx.x * 16, y0 = blockIdx.y * 16, b = blockIdx.z;
    float acc[49];
#pragma unroll
    for (int i = 0; i < 49; ++i) acc[i] = 0.f;

    for (int c0 = 0; c0 < 96; c0 += 4) {
        __syncthreads();
        {
            int gy = y0 + ty, gx = x0 + tx;
#pragma unroll
            for (int i = 0; i < 4; ++i)
                s1[ty][tx][i] = f1[((b * 96 + c0 + i) * HWHW) + gy * HW + gx];
        }
        for (int p = t; p < 22 * 22; p += 256) {
            int ry = p / 22, rx = p % 22;
            int gy = y0 + ry - 3, gx = x0 + rx - 3;
            bool v = ((unsigned)gy < (unsigned)HW) && ((unsigned)gx < (unsigned)HW);
            float4 vv = make_float4(0.f, 0.f, 0.f, 0.f);
            if (v) vv = ld_bf16x4(&f2[(size_t)((b * HW + gy) * HW + gx) * 96 + c0]);
            *(float4*)&s2[ry][rx][0] = vv;
        }
        __syncthreads();
        float4 v1 = *(const float4*)&s1[ty][tx][0];
#pragma unroll
        for (int dy = 0; dy < 7; ++dy) {
#pragma unroll
            for (int dx = 0; dx < 7; ++dx) {
                float4 v2 = *(const float4*)&s2[ty + dy][tx + dx][0];
                acc[dy * 7 + dx] += v1.x * v2.x + v1.y * v2.y + v1.z * v2.z + v1.w * v2.w;
            }
        }
    }
    int gy = y0 + ty, gx = x0 + tx;
    __hip_bfloat16* op = out + (size_t)((b * HW + gy) * HW + gx) * 64;
#pragma unroll
    for (int d0 = 0; d0 < 64; d0 += 4) {
        float vv[4];
#pragma unroll
        for (int j = 0; j < 4; ++j) {
            int d = d0 + j;
            float a = (d < 49) ? acc[d] * (1.0f / 96.0f) : 0.f;
            a = a >= 0.f ? a : 0.1f * a;
            vv[j] = a;
        }
        st_bf16x4(op + d0, make_float4(vv[0], vv[1], vv[2], vv[3]));
    }
}

// ---------------- MFMA implicit-GEMM 3x3 conv (m97-style 4x4 wave tile) ----------------
// wave tile: 4 px-tiles (rows) x WCO co-tiles of 16x16x32 => 64px x WCO*16 co
// block: 4 waves = WAVES_PX px-groups x WAVES_CO co-groups; block px = 16 cols x BR rows
// ky-split staging: per (ci-chunk, ky) stage 3-kx weights + BR input rows
template <int CIN, int COUT, int WAVES_CO, int WCO, int LEAKY>
__global__ __launch_bounds__(256) void convk(const __hip_bfloat16* __restrict__ in,
                                             const __hip_bfloat16* __restrict__ wg,
                                             const float* __restrict__ bias,
                                             __hip_bfloat16* __restrict__ out) {
    constexpr int WAVES_PX = 4 / WAVES_CO;
    constexpr int BR = WAVES_PX * 4;          // block rows of pixels
    constexpr int CIS = 36;                   // padded ci stride (72B -> 16-bank spread)
    static_assert(WAVES_CO * WCO * 16 == COUT, "one co-block covers all COUT");
    __shared__ __hip_bfloat16 s_in[BR * 18 * CIS];
    __shared__ __hip_bfloat16 s_w[3 * COUT * CIS];

    const int t = threadIdx.x;
    const int lane = t & 63;
    const int wave = t >> 6;
    const int q = lane >> 4;
    const int l16 = lane & 15;
    const int wr = wave % WAVES_PX;           // px row-group
    const int wc = wave / WAVES_PX;           // co group
    const int x0 = blockIdx.x * 16;
    const int y0 = blockIdx.y * BR;
    const int b = blockIdx.z;

    floatx4 acc[4][WCO];
#pragma unroll
    for (int i = 0; i < 4; ++i)
#pragma unroll
        for (int j = 0; j < WCO; ++j) acc[i][j] = (floatx4){0.f, 0.f, 0.f, 0.f};

    for (int ci0 = 0; ci0 < CIN; ci0 += 32) {
#pragma unroll
        for (int ky = 0; ky < 3; ++ky) {
            __syncthreads();
            // stage input rows [y0+ky-1 .. +BR-1], cols [x0-1 .. x0+16], 32 ci
            for (int ch = t; ch < BR * 18 * 4; ch += 256) {
                int c8 = (ch & 3) * 8;
                int px = ch >> 2;
                int s = px / 18, cc = px % 18;
                int gy = y0 + s + ky - 1, gx = x0 + cc - 1;
                uint4 u = make_uint4(0u, 0u, 0u, 0u);
                if ((unsigned)gy < (unsigned)HW && (unsigned)gx < (unsigned)HW)
                    u = *(const uint4*)&in[(size_t)((b * HW + gy) * HW + gx) * CIN + ci0 + c8];
                *(uint4*)&s_in[(s * 18 + cc) * CIS + c8] = u;
            }
            // stage weights [kx 0..2][COUT][32ci]
            for (int ch = t; ch < 3 * COUT * 4; ch += 256) {
                int c8 = (ch & 3) * 8;
                int co = (ch >> 2) % COUT;
                int kx = ch / (COUT * 4);
                *(uint4*)&s_w[(kx * COUT + co) * CIS + c8] =
                    *(const uint4*)&wg[(size_t)((ky * 3 + kx) * COUT + co) * CIN + ci0 + c8];
            }
            __syncthreads();
#pragma unroll
            for (int kx = 0; kx < 3; ++kx) {
                short8 A[WCO], B[4];
#pragma unroll
                for (int ct = 0; ct < WCO; ++ct)
                    A[ct] = *(const short8*)&s_w[(kx * COUT + wc * WCO * 16 + ct * 16 + l16) * CIS + q * 8];
#pragma unroll
                for (int pt = 0; pt < 4; ++pt)
                    B[pt] = *(const short8*)&s_in[((wr * 4 + pt) * 18 + l16 + kx) * CIS + q * 8];
#pragma unroll
                for (int pt = 0; pt < 4; ++pt)
#pragma unroll
                    for (int ct = 0; ct < WCO; ++ct)
                        acc[pt][ct] = __builtin_amdgcn_mfma_f32_16x16x32_bf16(A[ct], B[pt], acc[pt][ct], 0, 0, 0);
            }
        }
    }
    // epilogue: D col(lane&15)=pixel col, row(q*4+reg)=co within tile
#pragma unroll
    for (int pt = 0; pt < 4; ++pt) {
        int y = y0 + wr * 4 + pt;
        int x = x0 + l16;
        size_t pixbase = (size_t)((b * HW + y) * HW + x) * COUT;
#pragma unroll
        for (int ct = 0; ct < WCO; ++ct) {
            int co4 = wc * WCO * 16 + ct * 16 + q * 4;
            float4 bv = *(const float4*)&bias[co4];
            float r[4];
#pragma unroll
            for (int reg = 0; reg < 4; ++reg) {
                float vv = acc[pt][ct][reg] + ((const float*)&bv)[reg];
                if (LEAKY) vv = vv >= 0.f ? vv : 0.1f * vv;
                r[reg] = vv;
            }
            uint2 u;
            u.x = pack_bf2(r[0], r[1]);
            u.y = pack_bf2(r[2], r[3]);
            *(uint2*)&out[pixbase + co4] = u;
        }
    }
}

// ---------------- conv4: 5x5, 32->2, pad 2, NHWC32 bf16 in, + bias + flow residual ----------------
__global__ __launch_bounds__(256) void conv4_kernel(const __hip_bfloat16* __restrict__ in,
                                                    const float* __restrict__ wg,
                                                    const float* __restrict__ bias,
                                                    const float* __restrict__ flow,
                                                    float* __restrict__ out) {
    __shared__ float s_in[20 * 20 * 36];
    __shared__ float s_w[2 * 25 * 32];
    int t = threadIdx.x;
    int tx = t % 16, ty = t / 16;
    int x0 = blockIdx.x * 16, y0 = blockIdx.y * 16, b = blockIdx.z;
    for (int ch = t; ch < 400 * 4; ch += 256) {
        int px = ch >> 2;
        int c8 = (ch & 3) * 8;
        int ry = px / 20, rx = px % 20;
        int gy = y0 + ry - 2, gx = x0 + rx - 2;
        float4 lo = make_float4(0.f, 0.f, 0.f, 0.f), hi = lo;
        if ((unsigned)gy < (unsigned)HW && (unsigned)gx < (unsigned)HW) {
            const __hip_bfloat16* p = &in[(size_t)((b * HW + gy) * HW + gx) * 32 + c8];
            lo = ld_bf16x4(p);
            hi = ld_bf16x4(p + 4);
        }
        *(float4*)&s_in[px * 36 + c8] = lo;
        *(float4*)&s_in[px * 36 + c8 + 4] = hi;
    }
    for (int p = t; p < 1600; p += 256) {
        int ci = p % 32;
        int k = (p / 32) % 25;
        int co = p / 800;
        s_w[(co * 25 + k) * 32 + ci] = wg[(co * 32 + ci) * 25 + k];
    }
    __syncthreads();
    float acc0 = 0.f, acc1 = 0.f;
#pragma unroll
    for (int ky = 0; ky < 5; ++ky) {
#pragma unroll
        for (int kx = 0; kx < 5; ++kx) {
            int k = ky * 5 + kx;
            int base = ((ty + ky) * 20 + tx + kx) * 36;
#pragma unroll
            for (int c4 = 0; c4 < 32; c4 += 4) {
                float4 v = *(const float4*)&s_in[base + c4];
                float4 w0 = *(const float4*)&s_w[(0 * 25 + k) * 32 + c4];
                float4 w1 = *(const float4*)&s_w[(1 * 25 + k) * 32 + c4];
                acc0 += v.x * w0.x + v.y * w0.y + v.z * w0.z + v.w * w0.w;
                acc1 += v.x * w1.x + v.y * w1.y + v.z * w1.z + v.w * w1.w;
            }
        }
    }
    int gy = y0 + ty, gx = x0 + tx;
    int o0 = ((b * 2 + 0) * HWHW) + gy * HW + gx;
    int o1 = ((b * 2 + 1) * HWHW) + gy * HW + gx;
    out[o0] = acc0 + bias[0] + flow[o0];
    out[o1] = acc1 + bias[1] + flow[o1];
}

extern "C" void kernel_launch(void* const* d_in, const int* in_sizes, int n_in,
                              void* d_out, int out_size, void* d_ws, size_t ws_size,
                              hipStream_t stream) {
    (void)in_sizes; (void)n_in; (void)out_size; (void)ws_size;
    const float* f1      = (const float*)d_in[2];
    const float* f2in    = (const float*)d_in[3];
    const float* flow_in = (const float*)d_in[4];
    const float* w_up    = (const float*)d_in[5];
    const float* w1      = (const float*)d_in[6];
    const float* b1      = (const float*)d_in[7];
    const float* w2      = (const float*)d_in[8];
    const float* b2      = (const float*)d_in[9];
    const float* w3      = (const float*)d_in[10];
    const float* b3      = (const float*)d_in[11];
    const float* w4      = (const float*)d_in[12];
    const float* b4      = (const float*)d_in[13];
    float* out = (float*)d_out;
    char* ws = (char*)d_ws;

    // ws layout: flow fp32 [0,1179648) | w1b [1179648) | w2b [1327104) | w3b [1474560)
    //   R1 (feat2 NHWC96 / x1 NHWC128) [1511424, +37748736)
    //   R2 (corr/x2 NHWC64) [39260160, +18874368) | R3 (x3 NHWC32) [58134528, +9437184)
    float* flow = (float*)ws;
    __hip_bfloat16* w1b = (__hip_bfloat16*)(ws + 1179648);
    __hip_bfloat16* w2b = (__hip_bfloat16*)(ws + 1327104);
    __hip_bfloat16* w3b = (__hip_bfloat16*)(ws + 1474560);
    __hip_bfloat16* R1  = (__hip_bfloat16*)(ws + 1511424);
    __hip_bfloat16* R2  = (__hip_bfloat16*)(ws + 39260160);
    __hip_bfloat16* R3  = (__hip_bfloat16*)(ws + 58134528);

    upflow_kernel<<<1152, 256, 0, stream>>>(flow_in, w_up, flow);
    wprep_kernel<<<288, 256, 0, stream>>>(w1, w1b, 128, 49, 64);
    wprep_kernel<<<288, 256, 0, stream>>>(w2, w2b, 64, 128, 128);
    wprep_kernel<<<72, 256, 0, stream>>>(w3, w3b, 32, 64, 64);
    backwarp_kernel<<<dim3(576, 4), 256, 0, stream>>>(f2in, flow, R1);
    corr_kernel<<<dim3(12, 12, NB), 256, 0, stream>>>(f1, R1, R2);
    convk<64, 128, 2, 4, 1><<<dim3(12, 24, NB), 256, 0, stream>>>(R2, w1b, b1, R1);
    convk<128, 64, 1, 4, 1><<<dim3(12, 12, NB), 256, 0, stream>>>(R1, w2b, b2, R2);
    convk<64, 32, 1, 2, 1><<<dim3(12, 12, NB), 256, 0, stream>>>(R2, w3b, b3, R3);
    conv4_kernel<<<dim3(12, 12, NB), 256, 0, stream>>>(R3, w4, b4, flow, out);
}